// Round 1
// baseline (243.044 us; speedup 1.0000x reference)
//
#include <hip/hip_runtime.h>
#include <hip/hip_bf16.h>
#include <stdint.h>

typedef unsigned short u16;
typedef __attribute__((ext_vector_type(8))) short short8;   // 8 x bf16 (4 VGPRs) MFMA A/B frag
typedef __attribute__((ext_vector_type(4))) float floatx4;  // MFMA C/D frag

#define BATCH 4
#define SEQ   2048
#define DIM   1024

__device__ inline u16 f2bf(float f) {
  union { float f; uint32_t u; } v; v.f = f;
  uint32_t r = v.u + 0x7fffu + ((v.u >> 16) & 1u);  // RNE
  return (u16)(r >> 16);
}

// packed fp32x2 -> bf16x2 (v_cvt_pk_bf16_f32 on gfx950), RNE — bit-identical to f2bf
__device__ inline uint32_t f2bf2(float lo, float hi) {
  __hip_bfloat162 h = __float22bfloat162_rn(float2{lo, hi});
  union { __hip_bfloat162 h; uint32_t u; } v; v.h = h;
  return v.u;
}

// async global->LDS, 16B per lane; LDS dest is wave-uniform base (+lane*16 by HW)
__device__ inline void gload_lds16(const u16* g, u16* l) {
  __builtin_amdgcn_global_load_lds((const __attribute__((address_space(1))) uint32_t*)g,
                                   (__attribute__((address_space(3))) uint32_t*)l,
                                   16, 0, 0);
}

// ---------------- fused prep: x->bf16, W->Wt bf16, bias gather, lsum zero ----------------
// blocks [0,8192): cvt x.  blocks [8192,11264): transpose W (32x32 tile each).
__global__ __launch_bounds__(256) void prep(const float* __restrict__ x,
                                            const float* __restrict__ Wq,
                                            const float* __restrict__ Wk,
                                            const float* __restrict__ Wv,
                                            const float* __restrict__ bq,
                                            const float* __restrict__ bk,
                                            const float* __restrict__ bv,
                                            u16* __restrict__ Xb,
                                            u16* __restrict__ Wt,
                                            float* __restrict__ bias,
                                            float* __restrict__ lsum) {
  __shared__ u16 tile[32][33];
  const int bx = blockIdx.x;
  if (bx < 8192) {
    size_t i = ((size_t)bx * 256 + threadIdx.x) * 4;
    float4 v = *(const float4*)(x + i);
    uint2 o;
    o.x = f2bf2(v.x, v.y);
    o.y = f2bf2(v.z, v.w);
    *(uint2*)(Xb + i) = o;
    if (bx < 8) {  // zero 8192 floats of lsum
      float4 z = {0.f, 0.f, 0.f, 0.f};
      *(float4*)(lsum + (size_t)bx * 1024 + threadIdx.x * 4) = z;
    }
    return;
  }
  const int t = bx - 8192;
  const int tz = t >> 10;            // 0..2  (weight index)
  const int bxx = t & 31;            // 32 col-tiles
  const int byy = (t >> 5) & 31;     // 32 row-tiles
  const float* W = (tz == 0) ? Wq : (tz == 1) ? Wk : Wv;
  u16* o = Wt + (size_t)tz * (1u << 20);
  if (bxx == 0 && byy == 0) {  // pack biases contiguously
    const float* bsrc = (tz == 0) ? bq : (tz == 1) ? bk : bv;
    float4 b4 = *(const float4*)(bsrc + threadIdx.x * 4);
    *(float4*)(bias + tz * 1024 + threadIdx.x * 4) = b4;
  }
  int c0 = bxx * 32, r0 = byy * 32;
  int tx = threadIdx.x & 31, ty = threadIdx.x >> 5;  // ty 0..7
#pragma unroll
  for (int p = 0; p < 4; ++p)
    tile[p * 8 + ty][tx] = f2bf(W[(size_t)(r0 + p * 8 + ty) * DIM + c0 + tx]);
  __syncthreads();
#pragma unroll
  for (int p = 0; p < 4; ++p)
    o[(size_t)(c0 + p * 8 + ty) * DIM + r0 + tx] = tile[tx][p * 8 + ty];
}

// ---------------- pipelined GEMM core ----------------
// 8 waves (2M x 4N), per-wave TM/2 x 64 output, BK=32, ring-4 LDS K-tile buffers,
// counted vmcnt (never 0 in main loop).  C[m][n] = sum_k A[m][k]*B[n][k] (both B^T-layout).
//
// LDS per ring slot: A TM x 32 bf16 + B 256 x 32 bf16, 64B rows.
// Bank-conflict swizzle: LDS 16B-chunk c of row r holds global k-chunk c ^ ((r>>1)&3)
// (involution).  Applied on the GLOBAL SOURCE address at staging (global_load_lds dest
// must stay linear) and on the ds_read address — both sides, same XOR.
//
// Per K-tile t:  issue stage(t+3) -> ds_read frags(t) -> MFMA (setprio) ->
//   lgkmcnt(0) + sched_barrier(0) -> vmcnt(2 tiles) -> s_barrier.
// Race proof: stage(t+3) writes buf[(t+3)&3] == buf[(t-1)&3]; all reads of tile t-1
// were drained by iter t-1's lgkmcnt(0) before its barrier, and the stage is issued
// after that barrier.  Tile t's own loads were drained by iter t-1's counted vmcnt.

template <int TM>
__device__ inline void stage_tile(const u16* __restrict__ A, const u16* __restrict__ B,
                                  int K, int kbase, u16* buf, int tid, int kc) {
  const int wave = tid >> 6;
  const int r = tid >> 2;                         // 4 lanes per 64B row
  const u16* ga = A + (size_t)r * K + kbase + kc;
  u16* la = buf + wave * 512;                     // wave-uniform LDS base (u16 units)
#pragma unroll
  for (int i = 0; i < TM / 128; ++i)
    gload_lds16(ga + (size_t)(i * 128) * K, la + i * 4096);
  const u16* gb = B + (size_t)r * K + kbase + kc;
  u16* lb = buf + TM * 32 + wave * 512;
#pragma unroll
  for (int i = 0; i < 2; ++i)
    gload_lds16(gb + (size_t)(i * 128) * K, lb + i * 4096);
}

template <int TM>
__device__ inline void gemm_pipe(const u16* __restrict__ Ab, const u16* __restrict__ Bb,
                                 int K, u16* lds, floatx4 (&acc)[TM / 32][4]) {
  constexpr int MI = TM / 32;
  constexpr int BUFSZ = (TM + 256) * 32;          // u16 per ring slot
  const int tid = threadIdx.x;
  const int lane = tid & 63;
  const int wave = tid >> 6;
  const int wm = (wave >> 2) * (TM / 2);
  const int wn = (wave & 3) * 64;
  const int fr = lane & 15;
  // swizzled per-lane frag offset: row fr, k-chunk (lane>>4), chunk XOR (fr>>1)&3
  const int loff = fr * 32 + ((((lane >> 4) ^ ((fr >> 1) & 3))) << 3);
  // staging source k-chunk (pre-swizzle, involution of the read XOR)
  const int kc = ((tid & 3) ^ ((tid >> 3) & 3)) * 8;
  const int NT = K >> 5;

  stage_tile<TM>(Ab, Bb, K, 0, lds, tid, kc);
  stage_tile<TM>(Ab, Bb, K, 32, lds + BUFSZ, tid, kc);
  stage_tile<TM>(Ab, Bb, K, 64, lds + 2 * BUFSZ, tid, kc);
  if constexpr (TM == 256) asm volatile("s_waitcnt vmcnt(8)" ::: "memory");
  else                     asm volatile("s_waitcnt vmcnt(6)" ::: "memory");
  asm volatile("s_barrier" ::: "memory");

  for (int t = 0; t < NT; ++t) {
    if (t + 3 < NT)
      stage_tile<TM>(Ab, Bb, K, (t + 3) * 32, lds + ((t + 3) & 3) * BUFSZ, tid, kc);
    const u16* bA = lds + (t & 3) * BUFSZ;
    const u16* bB = bA + TM * 32;
    short8 a[MI], b[4];
#pragma unroll
    for (int i = 0; i < MI; ++i) a[i] = *(const short8*)(bA + (wm + i * 16) * 32 + loff);
#pragma unroll
    for (int i = 0; i < 4; ++i) b[i] = *(const short8*)(bB + (wn + i * 16) * 32 + loff);
    __builtin_amdgcn_s_setprio(1);
#pragma unroll
    for (int mi = 0; mi < MI; ++mi)
#pragma unroll
      for (int ni = 0; ni < 4; ++ni)
        acc[mi][ni] = __builtin_amdgcn_mfma_f32_16x16x32_bf16(a[mi], b[ni], acc[mi][ni], 0, 0, 0);
    __builtin_amdgcn_s_setprio(0);
    // all this wave's ds_reads done & nothing may sink past here (rule #18)
    asm volatile("s_waitcnt lgkmcnt(0)" ::: "memory");
    __builtin_amdgcn_sched_barrier(0);
    // counted vmcnt: drain tile t+1's loads, keep t+2/t+3 in flight
    if (t + 3 < NT) {
      if constexpr (TM == 256) asm volatile("s_waitcnt vmcnt(8)" ::: "memory");
      else                     asm volatile("s_waitcnt vmcnt(6)" ::: "memory");
    } else if (t + 2 < NT) {
      if constexpr (TM == 256) asm volatile("s_waitcnt vmcnt(4)" ::: "memory");
      else                     asm volatile("s_waitcnt vmcnt(3)" ::: "memory");
    } else if (t + 1 < NT) {
      asm volatile("s_waitcnt vmcnt(0)" ::: "memory");
    }
    asm volatile("s_barrier" ::: "memory");
  }
}

// ---------------- fused QKV + Vt projection, 256x256 tiles ----------------
// grid (128,1,3).  z in {0,1}: Q/K = Xb x Wt[z] + b (Q pre-scaled 1/32), 32m x 4n tiles.
// z==2: Vt[b][h][s] = Wv^T x^T + bv, 4m x 32n tiles, column-demuxed store.
__global__ __launch_bounds__(512, 2)
void qkv_fused(const u16* __restrict__ Xb, const u16* __restrict__ Wt,
               u16* __restrict__ Q, u16* __restrict__ Vt,
               const float* __restrict__ bias) {
  __shared__ __align__(16) u16 lds[4 * (256 + 256) * 32];  // 128 KiB
  constexpr int K = 1024;
  const int z = blockIdx.z;
  const int x = blockIdx.x;
  int mt, nt;
  if (z < 2) { mt = (x & 7) * 4 + ((x >> 3) & 3); nt = x >> 5; }   // XCD gets 4m x 4n
  else       { nt = (x & 7) * 4 + ((x >> 3) & 3); mt = x >> 5; }
  const u16* Ab; const u16* Bb;
  if (z < 2) {
    Ab = Xb + (size_t)mt * 256 * K;
    Bb = Wt + (size_t)z * (1u << 20) + (size_t)nt * 256 * K;
  } else {
    Ab = Wt + (size_t)2 * (1u << 20) + (size_t)mt * 256 * K;
    Bb = Xb + (size_t)nt * 256 * K;
  }

  floatx4 acc[8][4] = {};
  gemm_pipe<256>(Ab, Bb, K, lds, acc);

  const int lane = threadIdx.x & 63;
  const int wave = threadIdx.x >> 6;
  const int wm = (wave >> 2) * 128, wn = (wave & 3) * 64;
  const int er = (lane >> 4) * 4, ec = lane & 15;
  const int r0 = mt * 256 + wm;
  const int c0 = nt * 256 + wn;

  if (z < 2) {
    u16* C = Q + (size_t)z * (8u << 20);
    const float* bz = bias + z * 1024;
    const float zs = (z == 0) ? 0.03125f : 1.0f;  // fold 1/sqrt(1024) into Q
#pragma unroll
    for (int mi = 0; mi < 8; ++mi)
#pragma unroll
      for (int ni = 0; ni < 4; ++ni) {
        const int col = c0 + ni * 16 + ec;
        const float bb = bz[col];
        const int row = r0 + mi * 16 + er;
        const uint32_t p0 = f2bf2((acc[mi][ni][0] + bb) * zs, (acc[mi][ni][1] + bb) * zs);
        const uint32_t p1 = f2bf2((acc[mi][ni][2] + bb) * zs, (acc[mi][ni][3] + bb) * zs);
        C[(size_t)(row + 0) * 1024 + col] = (u16)p0;
        C[(size_t)(row + 1) * 1024 + col] = (u16)(p0 >> 16);
        C[(size_t)(row + 2) * 1024 + col] = (u16)p1;
        C[(size_t)(row + 3) * 1024 + col] = (u16)(p1 >> 16);
      }
  } else {
    const float* bz = bias + 2 * 1024;  // bv, indexed by row (=h)
#pragma unroll
    for (int mi = 0; mi < 8; ++mi) {
      float bb[4];
#pragma unroll
      for (int r = 0; r < 4; ++r) bb[r] = bz[r0 + mi * 16 + er + r];
#pragma unroll
      for (int ni = 0; ni < 4; ++ni) {
        const int col = c0 + ni * 16 + ec;
        const size_t base = (size_t)(col >> 11) * (1u << 21) + (col & 2047);
        const int row = r0 + mi * 16 + er;
        const uint32_t p0 = f2bf2(acc[mi][ni][0] + bb[0], acc[mi][ni][1] + bb[1]);
        const uint32_t p1 = f2bf2(acc[mi][ni][2] + bb[2], acc[mi][ni][3] + bb[3]);
        Vt[base + (size_t)(row + 0) * 2048] = (u16)p0;
        Vt[base + (size_t)(row + 1) * 2048] = (u16)(p0 >> 16);
        Vt[base + (size_t)(row + 2) * 2048] = (u16)p1;
        Vt[base + (size_t)(row + 3) * 2048] = (u16)(p1 >> 16);
      }
    }
  }
}

// ---------------- P~ = exp(Q K^T), 256x256 tiles, row sums -> lsum ----------------
// grid (64,1,4): per XCD 2m x 4n tiles per batch.
__global__ __launch_bounds__(512, 2)
void score_exp(const u16* __restrict__ Q, const u16* __restrict__ Kb,
               u16* __restrict__ P, float* __restrict__ lsum) {
  __shared__ __align__(16) u16 lds[4 * (256 + 256) * 32];  // 128 KiB
  const int z = blockIdx.z, x = blockIdx.x;
  const int c = x & 7, j = x >> 3;
  const int mt = 2 * (c & 3) + (j & 1);
  const int nt = 4 * (c >> 2) + (j >> 1);
  const u16* Ab = Q + (size_t)z * (2048 * 1024) + (size_t)mt * 256 * 1024;
  const u16* Bb = Kb + (size_t)z * (2048 * 1024) + (size_t)nt * 256 * 1024;

  floatx4 acc[8][4] = {};
  gemm_pipe<256>(Ab, Bb, 1024, lds, acc);

  const int lane = threadIdx.x & 63;
  const int wave = threadIdx.x >> 6;
  const int wm = (wave >> 2) * 128, wn = (wave & 3) * 64;
  const int er = (lane >> 4) * 4, ec = lane & 15;
  const int r0 = mt * 256 + wm;
  const int c0 = nt * 256 + wn;
  u16* C = P + (size_t)z * (4u << 20);
  float* lz = lsum + z * 2048;
#pragma unroll
  for (int mi = 0; mi < 8; ++mi) {
    float rs[4] = {0.f, 0.f, 0.f, 0.f};
#pragma unroll
    for (int ni = 0; ni < 4; ++ni) {
      const int col = c0 + ni * 16 + ec;
      const int row = r0 + mi * 16 + er;
      float e[4];
#pragma unroll
      for (int r = 0; r < 4; ++r) {
        e[r] = exp2f(acc[mi][ni][r] * 1.44269504088896340736f);
        rs[r] += e[r];
      }
      const uint32_t p0 = f2bf2(e[0], e[1]);
      const uint32_t p1 = f2bf2(e[2], e[3]);
      C[(size_t)(row + 0) * 2048 + col] = (u16)p0;
      C[(size_t)(row + 1) * 2048 + col] = (u16)(p0 >> 16);
      C[(size_t)(row + 2) * 2048 + col] = (u16)p1;
      C[(size_t)(row + 3) * 2048 + col] = (u16)(p1 >> 16);
    }
#pragma unroll
    for (int o = 1; o < 16; o <<= 1)
#pragma unroll
      for (int r = 0; r < 4; ++r) rs[r] += __shfl_xor(rs[r], o);
    if ((lane & 15) == 0) {
#pragma unroll
      for (int r = 0; r < 4; ++r)
        atomicAdd(&lz[r0 + mi * 16 + er + r], rs[r]);
    }
  }
}

// ---------------- out = (P~ Vt^T) / lsum[row], 128x256 tiles, fp32 out ----------------
// grid (64,1,4): per XCD 4m x 2n tiles per batch.  256 blocks -> perfect packing, no split-K.
__global__ __launch_bounds__(512, 2)
void pv_out(const u16* __restrict__ P, const u16* __restrict__ Vt,
            float* __restrict__ out, const float* __restrict__ lsum) {
  __shared__ __align__(16) u16 lds[4 * (128 + 256) * 32];  // 96 KiB
  const int z = blockIdx.z, x = blockIdx.x;
  const int c = x & 7, j = x >> 3;
  const int mt = 4 * (c >> 1) + (j & 3);
  const int nt = 2 * (c & 1) + (j >> 2);
  const u16* Ab = P + (size_t)z * (4u << 20) + (size_t)mt * 128 * 2048;
  const u16* Bb = Vt + (size_t)z * (2u << 20) + (size_t)nt * 256 * 2048;

  floatx4 acc[4][4] = {};
  gemm_pipe<128>(Ab, Bb, 2048, lds, acc);

  const int lane = threadIdx.x & 63;
  const int wave = threadIdx.x >> 6;
  const int wm = (wave >> 2) * 64, wn = (wave & 3) * 64;
  const int er = (lane >> 4) * 4, ec = lane & 15;
  const int r0 = mt * 128 + wm;
  const int c0 = nt * 256 + wn;
  float* C = out + (size_t)z * (2048 * 1024);
  const float* lz = lsum + z * 2048;
#pragma unroll
  for (int mi = 0; mi < 4; ++mi) {
    float inv[4];
#pragma unroll
    for (int r = 0; r < 4; ++r) inv[r] = 1.0f / lz[r0 + mi * 16 + er + r];
#pragma unroll
    for (int ni = 0; ni < 4; ++ni) {
      const int col = c0 + ni * 16 + ec;
#pragma unroll
      for (int r = 0; r < 4; ++r)
        C[(size_t)(r0 + mi * 16 + er + r) * 1024 + col] = acc[mi][ni][r] * inv[r];
    }
  }
}

extern "C" void kernel_launch(void* const* d_in, const int* in_sizes, int n_in,
                              void* d_out, int out_size, void* d_ws, size_t ws_size,
                              hipStream_t stream) {
  const float* x  = (const float*)d_in[0];
  const float* Wq = (const float*)d_in[1];
  const float* bq = (const float*)d_in[2];
  const float* Wk = (const float*)d_in[3];
  const float* bk = (const float*)d_in[4];
  const float* Wv = (const float*)d_in[5];
  const float* bv = (const float*)d_in[6];
  float* out = (float*)d_out;

  char* ws = (char*)d_ws;
  const size_t MB = 1ull << 20;
  u16* Q    = (u16*)(ws + 0 * MB);    // [2][8192][1024] bf16: Q,K contiguous
  u16* Kb   = (u16*)(ws + 16 * MB);
  u16* Vt   = (u16*)(ws + 48 * MB);   // [4][1024][2048]
  u16* Xb   = (u16*)(ws + 64 * MB);   // [8192][1024]
  u16* Wt   = (u16*)(ws + 80 * MB);   // [3][1024][1024]
  float* bias = (float*)(ws + 86 * MB);  // [3][1024]
  float* lsum = (float*)(ws + 87 * MB);  // [4][2048] softmax denominators
  u16* P    = (u16*)(ws + 88 * MB);   // [4][2048][2048] exp(scores), ends 120MB
  (void)ws_size; (void)in_sizes; (void)n_in; (void)out_size;

  // 1) fused prep: x->bf16, W->Wt, bias gather, lsum zero
  prep<<<11264, 256, 0, stream>>>(x, Wq, Wk, Wv, bq, bk, bv, Xb, Wt, bias, lsum);
  // 2) fused QKV + Vt projection (pipelined 256x256)
  qkv_fused<<<dim3(128, 1, 3), 512, 0, stream>>>(Xb, Wt, Q, Vt, bias);
  // 3) P~ = exp(Q K^T), row sums -> lsum (pipelined 256x256)
  score_exp<<<dim3(64, 1, 4), 512, 0, stream>>>(Q, Kb, P, lsum);
  // 4) out = (P~ V) / lsum[row] (pipelined 128x256)
  pv_out<<<dim3(64, 1, 4), 512, 0, stream>>>(P, Vt, out, lsum);
}

// Round 2
// 242.316 us; speedup vs baseline: 1.0030x; 1.0030x over previous
//
#include <hip/hip_runtime.h>
#include <hip/hip_bf16.h>
#include <stdint.h>

typedef unsigned short u16;
typedef __attribute__((ext_vector_type(8))) short short8;   // 8 x bf16 (4 VGPRs) MFMA A/B frag
typedef __attribute__((ext_vector_type(4))) float floatx4;  // MFMA C/D frag

#define BATCH 4
#define SEQ   2048
#define DIM   1024

__device__ inline u16 f2bf(float f) {
  union { float f; uint32_t u; } v; v.f = f;
  uint32_t r = v.u + 0x7fffu + ((v.u >> 16) & 1u);  // RNE
  return (u16)(r >> 16);
}

// packed fp32x2 -> bf16x2 (v_cvt_pk_bf16_f32 on gfx950), RNE — bit-identical to f2bf
__device__ inline uint32_t f2bf2(float lo, float hi) {
  __hip_bfloat162 h = __float22bfloat162_rn(float2{lo, hi});
  union { __hip_bfloat162 h; uint32_t u; } v; v.h = h;
  return v.u;
}

// async global->LDS, 16B per lane; LDS dest is wave-uniform base (+lane*16 by HW)
__device__ inline void gload_lds16(const u16* g, u16* l) {
  __builtin_amdgcn_global_load_lds((const __attribute__((address_space(1))) uint32_t*)g,
                                   (__attribute__((address_space(3))) uint32_t*)l,
                                   16, 0, 0);
}

// ---------------- fused prep: x->bf16, W->Wt bf16, bias gather, lsum zero ----------------
__global__ __launch_bounds__(256) void prep(const float* __restrict__ x,
                                            const float* __restrict__ Wq,
                                            const float* __restrict__ Wk,
                                            const float* __restrict__ Wv,
                                            const float* __restrict__ bq,
                                            const float* __restrict__ bk,
                                            const float* __restrict__ bv,
                                            u16* __restrict__ Xb,
                                            u16* __restrict__ Wt,
                                            float* __restrict__ bias,
                                            float* __restrict__ lsum) {
  __shared__ u16 tile[32][33];
  const int bx = blockIdx.x;
  if (bx < 8192) {
    size_t i = ((size_t)bx * 256 + threadIdx.x) * 4;
    float4 v = *(const float4*)(x + i);
    uint2 o;
    o.x = f2bf2(v.x, v.y);
    o.y = f2bf2(v.z, v.w);
    *(uint2*)(Xb + i) = o;
    if (bx < 8) {  // zero 8192 floats of lsum
      float4 z = {0.f, 0.f, 0.f, 0.f};
      *(float4*)(lsum + (size_t)bx * 1024 + threadIdx.x * 4) = z;
    }
    return;
  }
  const int t = bx - 8192;
  const int tz = t >> 10;            // 0..2  (weight index)
  const int bxx = t & 31;            // 32 col-tiles
  const int byy = (t >> 5) & 31;     // 32 row-tiles
  const float* W = (tz == 0) ? Wq : (tz == 1) ? Wk : Wv;
  u16* o = Wt + (size_t)tz * (1u << 20);
  if (bxx == 0 && byy == 0) {  // pack biases contiguously
    const float* bsrc = (tz == 0) ? bq : (tz == 1) ? bk : bv;
    float4 b4 = *(const float4*)(bsrc + threadIdx.x * 4);
    *(float4*)(bias + tz * 1024 + threadIdx.x * 4) = b4;
  }
  int c0 = bxx * 32, r0 = byy * 32;
  int tx = threadIdx.x & 31, ty = threadIdx.x >> 5;  // ty 0..7
#pragma unroll
  for (int p = 0; p < 4; ++p)
    tile[p * 8 + ty][tx] = f2bf(W[(size_t)(r0 + p * 8 + ty) * DIM + c0 + tx]);
  __syncthreads();
#pragma unroll
  for (int p = 0; p < 4; ++p)
    o[(size_t)(c0 + p * 8 + ty) * DIM + r0 + tx] = tile[tx][p * 8 + ty];
}

// ---------------- pipelined GEMM core (sub-phase frag pipelining) ----------------
// 8 waves (2M x 4N), per-wave TM/2 x 64 output, BK=32, ring-4 LDS K-tile buffers.
// Counted vmcnt leaves exactly tile t+3 in flight (t+1, t+2 drained by end of iter t),
// so iter t may ds_read tile t+1's frags.  Sub-phases:
//   p0: stage(t+3); read aH1(t); MFMA aH0(t) x b(t); lgkm(0)+schedbar
//   p1: read aH0(t+1)+b(t+1);    MFMA aH1(t) x b(t); lgkm(0)+schedbar; vmcnt(LPT); s_barrier
// Each lgkmcnt(0) covers only the batch issued just before 16 MFMAs -> LDS drains under MFMA.
// Slot safety: stage(t+3) reuses slot (t-1)&3, last read at iter t-2 p1 (2 barriers ago).
// Swizzle (verified 0 conflicts): LDS 16B-chunk c of row r holds global chunk c ^ ((r>>1)&3);
// pre-swizzled global source at staging (linear gload_lds dest), same XOR on ds_read.

template <int TM>
__device__ inline void stage_tile(const u16* __restrict__ A, const u16* __restrict__ B,
                                  int K, int kbase, u16* buf, int tid, int kc) {
  const int wave = tid >> 6;
  const int r = tid >> 2;                         // 4 lanes per 64B row
  const u16* ga = A + (size_t)r * K + kbase + kc;
  u16* la = buf + wave * 512;                     // wave-uniform LDS base (u16 units)
#pragma unroll
  for (int i = 0; i < TM / 128; ++i)
    gload_lds16(ga + (size_t)(i * 128) * K, la + i * 4096);
  const u16* gb = B + (size_t)r * K + kbase + kc;
  u16* lb = buf + TM * 32 + wave * 512;
#pragma unroll
  for (int i = 0; i < 2; ++i)
    gload_lds16(gb + (size_t)(i * 128) * K, lb + i * 4096);
}

#define WAITV_STEADY                                                            \
  if constexpr (TM == 256) asm volatile("s_waitcnt vmcnt(4)" ::: "memory");     \
  else                     asm volatile("s_waitcnt vmcnt(3)" ::: "memory");

// one K-tile: AA = aH0(t) regs, AB = aH1 buffer, BA = b(t) regs, BB = next-b buffer
#define TILE_BODY(T, AA, AB, BA, BB)                                              \
  {                                                                               \
    const int t_ = (T);                                                           \
    const u16* sA = lds + (size_t)(t_ & 3) * BUFSZ;                               \
    if (t_ + 3 < NT)                                                              \
      stage_tile<TM>(Ab, Bb, K, (t_ + 3) * 32, lds + ((t_ + 3) & 3) * BUFSZ, tid, kc); \
    _Pragma("unroll")                                                             \
    for (int i = 0; i < MH; ++i)                                                  \
      AB[i] = *(const short8*)(sA + (wm + (MH + i) * 16) * 32 + loff);            \
    __builtin_amdgcn_s_setprio(1);                                                \
    _Pragma("unroll")                                                             \
    for (int mi = 0; mi < MH; ++mi)                                               \
      _Pragma("unroll")                                                           \
      for (int ni = 0; ni < 4; ++ni)                                              \
        acc[mi][ni] = __builtin_amdgcn_mfma_f32_16x16x32_bf16(AA[mi], BA[ni], acc[mi][ni], 0, 0, 0); \
    __builtin_amdgcn_s_setprio(0);                                                \
    asm volatile("s_waitcnt lgkmcnt(0)" ::: "memory");                            \
    __builtin_amdgcn_sched_barrier(0);                                            \
    if (t_ + 1 < NT) {                                                            \
      const u16* nA = lds + (size_t)((t_ + 1) & 3) * BUFSZ;                       \
      const u16* nB = nA + TM * 32;                                               \
      _Pragma("unroll")                                                           \
      for (int i = 0; i < MH; ++i)                                                \
        AA[i] = *(const short8*)(nA + (wm + i * 16) * 32 + loff);                 \
      _Pragma("unroll")                                                           \
      for (int i = 0; i < 4; ++i)                                                 \
        BB[i] = *(const short8*)(nB + (wn + i * 16) * 32 + loff);                 \
    }                                                                             \
    __builtin_amdgcn_s_setprio(1);                                                \
    _Pragma("unroll")                                                             \
    for (int mi = 0; mi < MH; ++mi)                                               \
      _Pragma("unroll")                                                           \
      for (int ni = 0; ni < 4; ++ni)                                              \
        acc[MH + mi][ni] = __builtin_amdgcn_mfma_f32_16x16x32_bf16(AB[mi], BA[ni], acc[MH + mi][ni], 0, 0, 0); \
    __builtin_amdgcn_s_setprio(0);                                                \
    asm volatile("s_waitcnt lgkmcnt(0)" ::: "memory");                            \
    __builtin_amdgcn_sched_barrier(0);                                            \
    if (t_ + 3 < NT) { WAITV_STEADY }                                             \
    else { asm volatile("s_waitcnt vmcnt(0)" ::: "memory"); }                     \
    asm volatile("s_barrier" ::: "memory");                                       \
  }

template <int TM>
__device__ inline void gemm_pipe(const u16* __restrict__ Ab, const u16* __restrict__ Bb,
                                 int K, u16* lds, floatx4 (&acc)[TM / 32][4]) {
  constexpr int MI = TM / 32;
  constexpr int MH = MI / 2;
  constexpr int BUFSZ = (TM + 256) * 32;          // u16 per ring slot
  const int tid = threadIdx.x;
  const int lane = tid & 63;
  const int wave = tid >> 6;
  const int wm = (wave >> 2) * (TM / 2);
  const int wn = (wave & 3) * 64;
  const int fr = lane & 15;
  const int loff = fr * 32 + ((((lane >> 4) ^ ((fr >> 1) & 3))) << 3);
  const int kc = ((tid & 3) ^ ((tid >> 3) & 3)) * 8;
  const int NT = K >> 5;

  stage_tile<TM>(Ab, Bb, K, 0,  lds + (size_t)0 * BUFSZ, tid, kc);
  stage_tile<TM>(Ab, Bb, K, 32, lds + (size_t)1 * BUFSZ, tid, kc);
  stage_tile<TM>(Ab, Bb, K, 64, lds + (size_t)2 * BUFSZ, tid, kc);
  WAITV_STEADY                                     // drain tiles 0,1; leave tile 2 in flight
  asm volatile("s_barrier" ::: "memory");

  short8 Aa[MH], Ah[MH], Ba[4], Bn[4];
  {  // preload tile-0 frags: aH0 and b
    const u16* sA = lds;
    const u16* sB = lds + TM * 32;
#pragma unroll
    for (int i = 0; i < MH; ++i) Aa[i] = *(const short8*)(sA + (wm + i * 16) * 32 + loff);
#pragma unroll
    for (int i = 0; i < 4; ++i)  Ba[i] = *(const short8*)(sB + (wn + i * 16) * 32 + loff);
    asm volatile("s_waitcnt lgkmcnt(0)" ::: "memory");
    __builtin_amdgcn_sched_barrier(0);
  }

  for (int t = 0; t < NT; t += 2) {
    TILE_BODY(t,     Aa, Ah, Ba, Bn);
    TILE_BODY(t + 1, Aa, Ah, Bn, Ba);
  }
}

// ---------------- fused QKV + Vt projection, 256x256 tiles ----------------
__global__ __launch_bounds__(512, 2)
void qkv_fused(const u16* __restrict__ Xb, const u16* __restrict__ Wt,
               u16* __restrict__ Q, u16* __restrict__ Vt,
               const float* __restrict__ bias) {
  __shared__ __align__(16) u16 lds[4 * (256 + 256) * 32];  // 128 KiB
  constexpr int K = 1024;
  const int z = blockIdx.z;
  const int x = blockIdx.x;
  int mt, nt;
  if (z < 2) { mt = (x & 7) * 4 + ((x >> 3) & 3); nt = x >> 5; }   // XCD gets 4m x 4n
  else       { nt = (x & 7) * 4 + ((x >> 3) & 3); mt = x >> 5; }
  const u16* Abp; const u16* Bbp;
  if (z < 2) {
    Abp = Xb + (size_t)mt * 256 * K;
    Bbp = Wt + (size_t)z * (1u << 20) + (size_t)nt * 256 * K;
  } else {
    Abp = Wt + (size_t)2 * (1u << 20) + (size_t)mt * 256 * K;
    Bbp = Xb + (size_t)nt * 256 * K;
  }

  floatx4 acc[8][4] = {};
  gemm_pipe<256>(Abp, Bbp, K, lds, acc);

  const int lane = threadIdx.x & 63;
  const int wave = threadIdx.x >> 6;
  const int wm = (wave >> 2) * 128, wn = (wave & 3) * 64;
  const int er = (lane >> 4) * 4, ec = lane & 15;
  const int r0 = mt * 256 + wm;
  const int c0 = nt * 256 + wn;

  if (z < 2) {
    u16* C = Q + (size_t)z * (8u << 20);
    const float* bz = bias + z * 1024;
    const float zs = (z == 0) ? 0.03125f : 1.0f;  // fold 1/sqrt(1024) into Q
#pragma unroll
    for (int mi = 0; mi < 8; ++mi)
#pragma unroll
      for (int ni = 0; ni < 4; ++ni) {
        const int col = c0 + ni * 16 + ec;
        const float bb = bz[col];
        const int row = r0 + mi * 16 + er;
        const uint32_t p0 = f2bf2((acc[mi][ni][0] + bb) * zs, (acc[mi][ni][1] + bb) * zs);
        const uint32_t p1 = f2bf2((acc[mi][ni][2] + bb) * zs, (acc[mi][ni][3] + bb) * zs);
        C[(size_t)(row + 0) * 1024 + col] = (u16)p0;
        C[(size_t)(row + 1) * 1024 + col] = (u16)(p0 >> 16);
        C[(size_t)(row + 2) * 1024 + col] = (u16)p1;
        C[(size_t)(row + 3) * 1024 + col] = (u16)(p1 >> 16);
      }
  } else {
    const float* bz = bias + 2 * 1024;  // bv, indexed by row (=h)
#pragma unroll
    for (int mi = 0; mi < 8; ++mi) {
      float bb[4];
#pragma unroll
      for (int r = 0; r < 4; ++r) bb[r] = bz[r0 + mi * 16 + er + r];
#pragma unroll
      for (int ni = 0; ni < 4; ++ni) {
        const int col = c0 + ni * 16 + ec;
        const size_t base = (size_t)(col >> 11) * (1u << 21) + (col & 2047);
        const int row = r0 + mi * 16 + er;
        const uint32_t p0 = f2bf2(acc[mi][ni][0] + bb[0], acc[mi][ni][1] + bb[1]);
        const uint32_t p1 = f2bf2(acc[mi][ni][2] + bb[2], acc[mi][ni][3] + bb[3]);
        Vt[base + (size_t)(row + 0) * 2048] = (u16)p0;
        Vt[base + (size_t)(row + 1) * 2048] = (u16)(p0 >> 16);
        Vt[base + (size_t)(row + 2) * 2048] = (u16)p1;
        Vt[base + (size_t)(row + 3) * 2048] = (u16)(p1 >> 16);
      }
    }
  }
}

// ---------------- P~ = exp(Q K^T), 256x256 tiles, row sums -> lsum ----------------
__global__ __launch_bounds__(512, 2)
void score_exp(const u16* __restrict__ Q, const u16* __restrict__ Kb,
               u16* __restrict__ P, float* __restrict__ lsum) {
  __shared__ __align__(16) u16 lds[4 * (256 + 256) * 32];  // 128 KiB
  const int z = blockIdx.z, x = blockIdx.x;
  const int c = x & 7, j = x >> 3;
  const int mt = 2 * (c & 3) + (j & 1);
  const int nt = 4 * (c >> 2) + (j >> 1);
  const u16* Abp = Q + (size_t)z * (2048 * 1024) + (size_t)mt * 256 * 1024;
  const u16* Bbp = Kb + (size_t)z * (2048 * 1024) + (size_t)nt * 256 * 1024;

  floatx4 acc[8][4] = {};
  gemm_pipe<256>(Abp, Bbp, 1024, lds, acc);

  const int lane = threadIdx.x & 63;
  const int wave = threadIdx.x >> 6;
  const int wm = (wave >> 2) * 128, wn = (wave & 3) * 64;
  const int er = (lane >> 4) * 4, ec = lane & 15;
  const int r0 = mt * 256 + wm;
  const int c0 = nt * 256 + wn;
  u16* C = P + (size_t)z * (4u << 20);
  float* lz = lsum + z * 2048;
#pragma unroll
  for (int mi = 0; mi < 8; ++mi) {
    float rs[4] = {0.f, 0.f, 0.f, 0.f};
#pragma unroll
    for (int ni = 0; ni < 4; ++ni) {
      const int col = c0 + ni * 16 + ec;
      const int row = r0 + mi * 16 + er;
      float e[4];
#pragma unroll
      for (int r = 0; r < 4; ++r) {
        e[r] = exp2f(acc[mi][ni][r] * 1.44269504088896340736f);
        rs[r] += e[r];
      }
      const uint32_t p0 = f2bf2(e[0], e[1]);
      const uint32_t p1 = f2bf2(e[2], e[3]);
      C[(size_t)(row + 0) * 2048 + col] = (u16)p0;
      C[(size_t)(row + 1) * 2048 + col] = (u16)(p0 >> 16);
      C[(size_t)(row + 2) * 2048 + col] = (u16)p1;
      C[(size_t)(row + 3) * 2048 + col] = (u16)(p1 >> 16);
    }
#pragma unroll
    for (int o = 1; o < 16; o <<= 1)
#pragma unroll
      for (int r = 0; r < 4; ++r) rs[r] += __shfl_xor(rs[r], o);
    if ((lane & 15) == 0) {
#pragma unroll
      for (int r = 0; r < 4; ++r)
        atomicAdd(&lz[r0 + mi * 16 + er + r], rs[r]);
    }
  }
}

// ---------------- out = (P~ Vt^T) / lsum[row], 128x256 tiles, fp32 out ----------------
__global__ __launch_bounds__(512, 2)
void pv_out(const u16* __restrict__ P, const u16* __restrict__ Vt,
            float* __restrict__ out, const float* __restrict__ lsum) {
  __shared__ __align__(16) u16 lds[4 * (128 + 256) * 32];  // 96 KiB
  const int z = blockIdx.z, x = blockIdx.x;
  const int c = x & 7, j = x >> 3;
  const int mt = 4 * (c >> 1) + (j & 3);
  const int nt = 2 * (c & 1) + (j >> 2);
  const u16* Abp = P + (size_t)z * (4u << 20) + (size_t)mt * 128 * 2048;
  const u16* Bbp = Vt + (size_t)z * (2u << 20) + (size_t)nt * 256 * 2048;

  floatx4 acc[4][4] = {};
  gemm_pipe<128>(Abp, Bbp, 2048, lds, acc);

  const int lane = threadIdx.x & 63;
  const int wave = threadIdx.x >> 6;
  const int wm = (wave >> 2) * 64, wn = (wave & 3) * 64;
  const int er = (lane >> 4) * 4, ec = lane & 15;
  const int r0 = mt * 128 + wm;
  const int c0 = nt * 256 + wn;
  float* C = out + (size_t)z * (2048 * 1024);
  const float* lz = lsum + z * 2048;
#pragma unroll
  for (int mi = 0; mi < 4; ++mi) {
    float inv[4];
#pragma unroll
    for (int r = 0; r < 4; ++r) inv[r] = 1.0f / lz[r0 + mi * 16 + er + r];
#pragma unroll
    for (int ni = 0; ni < 4; ++ni) {
      const int col = c0 + ni * 16 + ec;
#pragma unroll
      for (int r = 0; r < 4; ++r)
        C[(size_t)(r0 + mi * 16 + er + r) * 1024 + col] = acc[mi][ni][r] * inv[r];
    }
  }
}

extern "C" void kernel_launch(void* const* d_in, const int* in_sizes, int n_in,
                              void* d_out, int out_size, void* d_ws, size_t ws_size,
                              hipStream_t stream) {
  const float* x  = (const float*)d_in[0];
  const float* Wq = (const float*)d_in[1];
  const float* bq = (const float*)d_in[2];
  const float* Wk = (const float*)d_in[3];
  const float* bk = (const float*)d_in[4];
  const float* Wv = (const float*)d_in[5];
  const float* bv = (const float*)d_in[6];
  float* out = (float*)d_out;

  char* ws = (char*)d_ws;
  const size_t MB = 1ull << 20;
  u16* Q    = (u16*)(ws + 0 * MB);    // [2][8192][1024] bf16: Q,K contiguous
  u16* Kb   = (u16*)(ws + 16 * MB);
  u16* Vt   = (u16*)(ws + 48 * MB);   // [4][1024][2048]
  u16* Xb   = (u16*)(ws + 64 * MB);   // [8192][1024]
  u16* Wt   = (u16*)(ws + 80 * MB);   // [3][1024][1024]
  float* bias = (float*)(ws + 86 * MB);  // [3][1024]
  float* lsum = (float*)(ws + 87 * MB);  // [4][2048] softmax denominators
  u16* P    = (u16*)(ws + 88 * MB);   // [4][2048][2048] exp(scores), ends 120MB
  (void)ws_size; (void)in_sizes; (void)n_in; (void)out_size;

  // 1) fused prep: x->bf16, W->Wt, bias gather, lsum zero
  prep<<<11264, 256, 0, stream>>>(x, Wq, Wk, Wv, bq, bk, bv, Xb, Wt, bias, lsum);
  // 2) fused QKV + Vt projection (sub-phase pipelined 256x256)
  qkv_fused<<<dim3(128, 1, 3), 512, 0, stream>>>(Xb, Wt, Q, Vt, bias);
  // 3) P~ = exp(Q K^T), row sums -> lsum (sub-phase pipelined 256x256)
  score_exp<<<dim3(64, 1, 4), 512, 0, stream>>>(Q, Kb, P, lsum);
  // 4) out = (P~ V) / lsum[row] (sub-phase pipelined 128x256)
  pv_out<<<dim3(64, 1, 4), 512, 0, stream>>>(P, Vt, out, lsum);
}

// Round 3
// 234.274 us; speedup vs baseline: 1.0374x; 1.0343x over previous
//
#include <hip/hip_runtime.h>
#include <hip/hip_bf16.h>
#include <stdint.h>

typedef unsigned short u16;
typedef __attribute__((ext_vector_type(8))) short short8;   // 8 x bf16 (4 VGPRs) MFMA A/B frag
typedef __attribute__((ext_vector_type(4))) float floatx4;  // MFMA C/D frag

#define DIM 1024

__device__ inline u16 f2bf(float f) {
  union { float f; uint32_t u; } v; v.f = f;
  uint32_t r = v.u + 0x7fffu + ((v.u >> 16) & 1u);  // RNE
  return (u16)(r >> 16);
}

// packed fp32x2 -> bf16x2 (v_cvt_pk_bf16_f32 on gfx950), RNE — bit-identical to f2bf
__device__ inline uint32_t f2bf2(float lo, float hi) {
  __hip_bfloat162 h = __float22bfloat162_rn(float2{lo, hi});
  union { __hip_bfloat162 h; uint32_t u; } v; v.h = h;
  return v.u;
}

// async global->LDS, 16B per lane; LDS dest is wave-uniform base (+lane*16 by HW)
__device__ inline void gload_lds16(const u16* g, u16* l) {
  __builtin_amdgcn_global_load_lds((const __attribute__((address_space(1))) uint32_t*)g,
                                   (__attribute__((address_space(3))) uint32_t*)l,
                                   16, 0, 0);
}

#define LGKM0 asm volatile("s_waitcnt lgkmcnt(0)" ::: "memory")
#define VMW(n) asm volatile("s_waitcnt vmcnt(" #n ")" ::: "memory")
#define BAR() do { asm volatile("" ::: "memory"); __builtin_amdgcn_s_barrier(); asm volatile("" ::: "memory"); } while (0)
#define PRIO1 __builtin_amdgcn_s_setprio(1)
#define PRIO0 __builtin_amdgcn_s_setprio(0)

// ---------------- fused prep: x->bf16, W->Wt bf16, bias gather, lsum zero ----------------
__global__ __launch_bounds__(256) void prep(const float* __restrict__ x,
                                            const float* __restrict__ Wq,
                                            const float* __restrict__ Wk,
                                            const float* __restrict__ Wv,
                                            const float* __restrict__ bq,
                                            const float* __restrict__ bk,
                                            const float* __restrict__ bv,
                                            u16* __restrict__ Xb,
                                            u16* __restrict__ Wt,
                                            float* __restrict__ bias,
                                            float* __restrict__ lsum) {
  __shared__ u16 tile[32][33];
  const int bx = blockIdx.x;
  if (bx < 8192) {
    size_t i = ((size_t)bx * 256 + threadIdx.x) * 4;
    float4 v = *(const float4*)(x + i);
    uint2 o;
    o.x = f2bf2(v.x, v.y);
    o.y = f2bf2(v.z, v.w);
    *(uint2*)(Xb + i) = o;
    if (bx < 8) {  // zero 8192 floats of lsum
      float4 z = {0.f, 0.f, 0.f, 0.f};
      *(float4*)(lsum + (size_t)bx * 1024 + threadIdx.x * 4) = z;
    }
    return;
  }
  const int t = bx - 8192;
  const int tz = t >> 10;            // 0..2  (weight index)
  const int bxx = t & 31;            // 32 col-tiles
  const int byy = (t >> 5) & 31;     // 32 row-tiles
  const float* W = (tz == 0) ? Wq : (tz == 1) ? Wk : Wv;
  u16* o = Wt + (size_t)tz * (1u << 20);
  if (bxx == 0 && byy == 0) {  // pack biases contiguously
    const float* bsrc = (tz == 0) ? bq : (tz == 1) ? bk : bv;
    float4 b4 = *(const float4*)(bsrc + threadIdx.x * 4);
    *(float4*)(bias + tz * 1024 + threadIdx.x * 4) = b4;
  }
  int c0 = bxx * 32, r0 = byy * 32;
  int tx = threadIdx.x & 31, ty = threadIdx.x >> 5;  // ty 0..7
#pragma unroll
  for (int p = 0; p < 4; ++p)
    tile[p * 8 + ty][tx] = f2bf(W[(size_t)(r0 + p * 8 + ty) * DIM + c0 + tx]);
  __syncthreads();
#pragma unroll
  for (int p = 0; p < 4; ++p)
    o[(size_t)(c0 + p * 8 + ty) * DIM + r0 + tx] = tile[tx][p * 8 + ty];
}

// ---------------- m201-style 8-phase 256x256 GEMM core, K=1024 (NT=16) ----------------
// 8 waves 2Mx4N, per-wave 128x64 out, BK=64, 2 LDS K-tile buffers (tile T -> buf T&1).
// LDS buffer: A[256][64] + B[256][64] bf16 = 64 KiB; 2 bufs = 128 KiB.
// Swizzle: 16B-chunk slot s of row r holds global k-chunk s^(r&7); source pre-swizzled
// at staging (gload_lds dest linear), same XOR on ds_read -> conflict-free b128.
// Phase = {ds-reads; stage 1 half-tile; barrier; lgkm(0); prio1; 16 MFMA; prio0; [gate]; barrier}.
// Stage slots (iter T,T+1): ph1/2: (T+1).A0/A1; ph3/4: (T+2).B0/B1; ph5/6: (T+2).A0/A1;
// ph7/8: (T+3).B0/B1.  Gates vmcnt(4) at ph4 (protects T+1 reads at ph5-8) and ph8
// (protects T+2 reads next iter).  Liveness: each overwritten half's last ds_read is
// lgkm(0)-drained >=1 barrier before its stage issues.
__device__ __forceinline__ void gemm1024_8ph(const u16* __restrict__ Ab,
                                             const u16* __restrict__ Bb,
                                             u16* __restrict__ lds,
                                             floatx4 (&acc)[8][4]) {
  constexpr int K = 1024;
  constexpr int BUF = 32768;  // u16 per buffer
  const int tid = threadIdx.x;
  const int lane = tid & 63;
  const int w = tid >> 6;
  const int wm = (w >> 2) * 128;
  const int wn = (w & 3) * 64;
  const int fr = lane & 15;
  const int sl0 = (((lane >> 4)    ) ^ (fr & 7)) * 8;
  const int sl1 = (((lane >> 4) | 4) ^ (fr & 7)) * 8;
  const int rA = (wm + fr) * 64;           // + mi*1024 + slot
  const int rB = 16384 + (wn + fr) * 64;   // + ni*1024 + slot
  const int srow = tid >> 3;               // staging row 0..63 (+64 per sub-load)
  const int kc = ((tid & 7) ^ (srow & 7)) * 8;  // pre-swizzled source chunk
  const u16* ga = Ab + (size_t)srow * K + kc;
  const u16* gb = Bb + (size_t)srow * K + kc;
  u16* const ld0 = lds + w * 512;          // wave-uniform staging base

  short8 Aq[4][2], Bp[2][2][2];

#define STG_A(B_, TT, h) { u16* d_ = ld0 + (B_) * BUF + (h) * 8192;               \
    const u16* s_ = ga + (size_t)((h) * 128) * K + (TT) * 64;                     \
    gload_lds16(s_, d_); gload_lds16(s_ + (size_t)64 * K, d_ + 4096); }
#define STG_B(B_, TT, h) { u16* d_ = ld0 + (B_) * BUF + 16384 + (h) * 8192;       \
    const u16* s_ = gb + (size_t)((h) * 128) * K + (TT) * 64;                     \
    gload_lds16(s_, d_); gload_lds16(s_ + (size_t)64 * K, d_ + 4096); }
#define RD_A(B_, q) { const u16* p_ = lds + (B_) * BUF + rA + (q) * 4096;         \
    _Pragma("unroll") for (int m_ = 0; m_ < 4; ++m_) {                            \
      Aq[m_][0] = *(const short8*)(p_ + m_ * 1024 + sl0);                         \
      Aq[m_][1] = *(const short8*)(p_ + m_ * 1024 + sl1); } }
#define RD_B(B_, p) { const u16* q_ = lds + (B_) * BUF + rB + (p) * 2048;         \
    _Pragma("unroll") for (int n_ = 0; n_ < 2; ++n_) {                            \
      Bp[p][n_][0] = *(const short8*)(q_ + n_ * 1024 + sl0);                      \
      Bp[p][n_][1] = *(const short8*)(q_ + n_ * 1024 + sl1); } }
#define MM(q, p)                                                                  \
    _Pragma("unroll") for (int m_ = 0; m_ < 4; ++m_)                              \
    _Pragma("unroll") for (int n_ = 0; n_ < 2; ++n_)                              \
    _Pragma("unroll") for (int s_ = 0; s_ < 2; ++s_)                              \
      acc[(q) * 4 + m_][(p) * 2 + n_] = __builtin_amdgcn_mfma_f32_16x16x32_bf16(  \
          Aq[m_][s_], Bp[p][n_][s_], acc[(q) * 4 + m_][(p) * 2 + n_], 0, 0, 0);

  // prologue: tile0 full + tile1 B; drain tile0 (leave tile1.B in flight)
  STG_A(0, 0, 0); STG_A(0, 0, 1); STG_B(0, 0, 0); STG_B(0, 0, 1);
  STG_B(1, 1, 0); STG_B(1, 1, 1);
  VMW(4);
  BAR();

  for (int j = 0; j < 8; ++j) {
    const int T = 2 * j;
    const bool nl = (j < 7);
    // ph1: tile T quad0 x pair0
    RD_A(0, 0); RD_B(0, 0);
    STG_A(1, T + 1, 0);
    BAR(); LGKM0;
    PRIO1; MM(0, 0); PRIO0;
    BAR();
    // ph2
    RD_B(0, 1);
    STG_A(1, T + 1, 1);
    BAR(); LGKM0;
    PRIO1; MM(0, 1); PRIO0;
    BAR();
    // ph3
    RD_A(0, 1);
    if (nl) STG_B(0, T + 2, 0);
    BAR(); LGKM0;
    PRIO1; MM(1, 0); PRIO0;
    BAR();
    // ph4  (gate: T+1 fully landed for ph5-8)
    if (nl) STG_B(0, T + 2, 1);
    BAR(); LGKM0;
    PRIO1; MM(1, 1); PRIO0;
    if (nl) { VMW(4); } else { VMW(0); }
    BAR();
    // ph5: tile T+1
    RD_A(1, 0); RD_B(1, 0);
    if (nl) STG_A(0, T + 2, 0);
    BAR(); LGKM0;
    PRIO1; MM(0, 0); PRIO0;
    BAR();
    // ph6
    RD_B(1, 1);
    if (nl) STG_A(0, T + 2, 1);
    BAR(); LGKM0;
    PRIO1; MM(0, 1); PRIO0;
    BAR();
    // ph7
    RD_A(1, 1);
    if (nl) STG_B(1, T + 3, 0);
    BAR(); LGKM0;
    PRIO1; MM(1, 0); PRIO0;
    BAR();
    // ph8  (gate: T+2 fully landed for next iter)
    if (nl) STG_B(1, T + 3, 1);
    BAR(); LGKM0;
    PRIO1; MM(1, 1); PRIO0;
    if (nl) { VMW(4); } else { VMW(0); }
    BAR();
  }
#undef STG_A
#undef STG_B
#undef RD_A
#undef RD_B
#undef MM
}

// ---------------- Q|K projection: [8192 x 2048] = Xb x (Wq|Wk)^T, 256 blocks ----------------
__global__ __launch_bounds__(512, 2)
void qk_proj(const u16* __restrict__ Xb, const u16* __restrict__ Wt,
             u16* __restrict__ Q, const float* __restrict__ bias) {
  __shared__ __align__(16) u16 lds[65536];  // 128 KiB
  const int x = blockIdx.x;
  const int c = x & 7, j = x >> 3;
  const int mt = c * 4 + (j & 3);   // 0..31
  const int nt = j >> 2;            // 0..7 over combined N=2048 (Wq then Wk contiguous)
  const u16* Ab = Xb + (size_t)mt * 262144;
  const u16* Bb = Wt + (size_t)nt * 262144;
  floatx4 acc[8][4] = {};
  gemm1024_8ph(Ab, Bb, lds, acc);

  const int lane = threadIdx.x & 63;
  const int w = threadIdx.x >> 6;
  const int wm = (w >> 2) * 128, wn = (w & 3) * 64;
  const int er = (lane >> 4) * 4, ec = lane & 15;
  const int r0 = mt * 256 + wm;
  const int z = nt >> 2;                      // 0=Q, 1=K
  const int c0 = (nt & 3) * 256 + wn;
  u16* C = Q + (size_t)z * (8u << 20);
  const float* bz = bias + z * 1024;
  const float zs = (z == 0) ? 0.03125f : 1.0f;  // fold 1/sqrt(1024) into Q
#pragma unroll
  for (int mi = 0; mi < 8; ++mi)
#pragma unroll
    for (int ni = 0; ni < 4; ++ni) {
      const int col = c0 + ni * 16 + ec;
      const float bb = bz[col];
      const int row = r0 + mi * 16 + er;
      const uint32_t p0 = f2bf2((acc[mi][ni][0] + bb) * zs, (acc[mi][ni][1] + bb) * zs);
      const uint32_t p1 = f2bf2((acc[mi][ni][2] + bb) * zs, (acc[mi][ni][3] + bb) * zs);
      C[(size_t)(row + 0) * 1024 + col] = (u16)p0;
      C[(size_t)(row + 1) * 1024 + col] = (u16)(p0 >> 16);
      C[(size_t)(row + 2) * 1024 + col] = (u16)p1;
      C[(size_t)(row + 3) * 1024 + col] = (u16)(p1 >> 16);
    }
}

// ---------------- combined Vt projection (128 tiles) + score P~=exp(QK^T) (256 tiles) ----------------
__global__ __launch_bounds__(512, 2)
void vt_score(const u16* __restrict__ Xb, const u16* __restrict__ Wt,
              const u16* __restrict__ Q, u16* __restrict__ Vt,
              u16* __restrict__ P, float* __restrict__ lsum,
              const float* __restrict__ bias) {
  __shared__ __align__(16) u16 lds[65536];  // 128 KiB
  const int x = blockIdx.x;
  const u16 *Ab, *Bb;
  int mt, nt, z = 0;
  if (x < 128) {            // Vt: [1024 x 8192] = Wv^T x Xb^T
    mt = x & 3; nt = x >> 2;
    Ab = Wt + (size_t)2 * (1u << 20) + (size_t)mt * 262144;
    Bb = Xb + (size_t)nt * 262144;
  } else {                  // score z: [2048 x 2048] = Q[z] x K[z]^T
    const int xs = x - 128;
    z = xs >> 6;
    const int q = xs & 63;
    const int c = q & 7, jj = q >> 3;
    mt = (c & 3) * 2 + (jj & 1);
    nt = (c >> 2) * 4 + (jj >> 1);
    Ab = Q + (size_t)z * 2097152 + (size_t)mt * 262144;
    Bb = Q + 8388608 + (size_t)z * 2097152 + (size_t)nt * 262144;
  }
  floatx4 acc[8][4] = {};
  gemm1024_8ph(Ab, Bb, lds, acc);

  const int lane = threadIdx.x & 63;
  const int w = threadIdx.x >> 6;
  const int wm = (w >> 2) * 128, wn = (w & 3) * 64;
  const int er = (lane >> 4) * 4, ec = lane & 15;
  const int r0 = mt * 256 + wm;
  const int c0 = nt * 256 + wn;

  if (x < 128) {
    const float* bz = bias + 2 * 1024;  // bv, indexed by row (=h)
#pragma unroll
    for (int mi = 0; mi < 8; ++mi) {
      float bb[4];
#pragma unroll
      for (int r = 0; r < 4; ++r) bb[r] = bz[r0 + mi * 16 + er + r];
#pragma unroll
      for (int ni = 0; ni < 4; ++ni) {
        const int col = c0 + ni * 16 + ec;  // global s in [0,8192)
        const size_t base = (size_t)(col >> 11) * (1u << 21) + (col & 2047);
        const int row = r0 + mi * 16 + er;
        const uint32_t p0 = f2bf2(acc[mi][ni][0] + bb[0], acc[mi][ni][1] + bb[1]);
        const uint32_t p1 = f2bf2(acc[mi][ni][2] + bb[2], acc[mi][ni][3] + bb[3]);
        Vt[base + (size_t)(row + 0) * 2048] = (u16)p0;
        Vt[base + (size_t)(row + 1) * 2048] = (u16)(p0 >> 16);
        Vt[base + (size_t)(row + 2) * 2048] = (u16)p1;
        Vt[base + (size_t)(row + 3) * 2048] = (u16)(p1 >> 16);
      }
    }
  } else {
    u16* C = P + (size_t)z * (4u << 20);
    float* lz = lsum + z * 2048;
#pragma unroll
    for (int mi = 0; mi < 8; ++mi) {
      float rs[4] = {0.f, 0.f, 0.f, 0.f};
#pragma unroll
      for (int ni = 0; ni < 4; ++ni) {
        const int col = c0 + ni * 16 + ec;
        const int row = r0 + mi * 16 + er;
        float e[4];
#pragma unroll
        for (int r = 0; r < 4; ++r) {
          e[r] = exp2f(acc[mi][ni][r] * 1.44269504088896340736f);
          rs[r] += e[r];
        }
        const uint32_t p0 = f2bf2(e[0], e[1]);
        const uint32_t p1 = f2bf2(e[2], e[3]);
        C[(size_t)(row + 0) * 2048 + col] = (u16)p0;
        C[(size_t)(row + 1) * 2048 + col] = (u16)(p0 >> 16);
        C[(size_t)(row + 2) * 2048 + col] = (u16)p1;
        C[(size_t)(row + 3) * 2048 + col] = (u16)(p1 >> 16);
      }
#pragma unroll
      for (int o = 1; o < 16; o <<= 1)
#pragma unroll
        for (int r = 0; r < 4; ++r) rs[r] += __shfl_xor(rs[r], o);
      if ((lane & 15) == 0) {
#pragma unroll
        for (int r = 0; r < 4; ++r)
          atomicAdd(&lz[r0 + mi * 16 + er + r], rs[r]);
      }
    }
  }
}

// ---------------- out = (P~ Vt^T)/lsum: 128x256 tiles, K=2048, 4-phase variant, 256 blocks ----------------
__global__ __launch_bounds__(512, 2)
void pv_out(const u16* __restrict__ P, const u16* __restrict__ Vt,
            float* __restrict__ out, const float* __restrict__ lsum) {
  __shared__ __align__(16) u16 lds[49152];  // 96 KiB: 2 x (A 128x64 + B 256x64)
  constexpr int K = 2048;
  constexpr int BUF = 24576;
  const int x = blockIdx.x;
  const int z = x >> 6, q = x & 63;
  const int c = q & 7, jj = q >> 3;
  const int mt = (c >> 1) * 4 + (jj & 3);   // 0..15
  const int nt = (c & 1) * 2 + (jj >> 2);   // 0..3
  const u16* Ab = P + (size_t)z * (4u << 20) + (size_t)mt * 128 * 2048;
  const u16* Bb = Vt + (size_t)z * (2u << 20) + (size_t)nt * 256 * 2048;

  const int tid = threadIdx.x;
  const int lane = tid & 63;
  const int w = tid >> 6;
  const int wm = (w >> 2) * 64;
  const int wn = (w & 3) * 64;
  const int fr = lane & 15;
  const int sl0 = (((lane >> 4)    ) ^ (fr & 7)) * 8;
  const int sl1 = (((lane >> 4) | 4) ^ (fr & 7)) * 8;
  const int rA = (wm + fr) * 64;
  const int rB = 8192 + (wn + fr) * 64;
  const int srow = tid >> 3;
  const int kc = ((tid & 7) ^ (srow & 7)) * 8;
  const u16* ga = Ab + (size_t)srow * K + kc;
  const u16* gb = Bb + (size_t)srow * K + kc;
  u16* const ld0 = lds + w * 512;

  short8 Aq[4][2], Bp[2][2][2];
  floatx4 acc[4][4] = {};

#define PSTG_A(B_, TT) { u16* d_ = ld0 + (B_) * BUF;                              \
    const u16* s_ = ga + (size_t)(TT) * 64;                                       \
    gload_lds16(s_, d_); gload_lds16(s_ + (size_t)64 * K, d_ + 4096); }
#define PSTG_B(B_, TT, h) { u16* d_ = ld0 + (B_) * BUF + 8192 + (h) * 8192;       \
    const u16* s_ = gb + (size_t)((h) * 128) * K + (TT) * 64;                     \
    gload_lds16(s_, d_); gload_lds16(s_ + (size_t)64 * K, d_ + 4096); }
#define PRD_A(B_) { const u16* p_ = lds + (B_) * BUF + rA;                        \
    _Pragma("unroll") for (int m_ = 0; m_ < 4; ++m_) {                            \
      Aq[m_][0] = *(const short8*)(p_ + m_ * 1024 + sl0);                         \
      Aq[m_][1] = *(const short8*)(p_ + m_ * 1024 + sl1); } }
#define PRD_B(B_, p) { const u16* q_ = lds + (B_) * BUF + rB + (p) * 2048;        \
    _Pragma("unroll") for (int n_ = 0; n_ < 2; ++n_) {                            \
      Bp[p][n_][0] = *(const short8*)(q_ + n_ * 1024 + sl0);                      \
      Bp[p][n_][1] = *(const short8*)(q_ + n_ * 1024 + sl1); } }
#define PMM(p)                                                                    \
    _Pragma("unroll") for (int m_ = 0; m_ < 4; ++m_)                              \
    _Pragma("unroll") for (int n_ = 0; n_ < 2; ++n_)                              \
    _Pragma("unroll") for (int s_ = 0; s_ < 2; ++s_)                              \
      acc[m_][(p) * 2 + n_] = __builtin_amdgcn_mfma_f32_16x16x32_bf16(            \
          Aq[m_][s_], Bp[p][n_][s_], acc[m_][(p) * 2 + n_], 0, 0, 0);

  // prologue: T0 {A,B} + T1 A; drain T0 (leave T1.A)
  PSTG_A(0, 0); PSTG_B(0, 0, 0); PSTG_B(0, 0, 1); PSTG_A(1, 1);
  VMW(2);
  BAR();

  for (int j = 0; j < 16; ++j) {
    const int T = 2 * j;
    const bool nl = (j < 15);
    // ph1: tile T, pair0
    PRD_A(0); PRD_B(0, 0);
    PSTG_B(1, T + 1, 0); PSTG_B(1, T + 1, 1);
    BAR(); LGKM0;
    PRIO1; PMM(0); PRIO0;
    BAR();
    // ph2: tile T, pair1  (gate: T+1 landed for ph3-4)
    PRD_B(0, 1);
    if (nl) PSTG_A(0, T + 2);
    BAR(); LGKM0;
    PRIO1; PMM(1); PRIO0;
    if (nl) { VMW(2); } else { VMW(0); }
    BAR();
    // ph3: tile T+1, pair0
    PRD_A(1); PRD_B(1, 0);
    if (nl) { PSTG_B(0, T + 2, 0); PSTG_B(0, T + 2, 1); }
    BAR(); LGKM0;
    PRIO1; PMM(0); PRIO0;
    BAR();
    // ph4: tile T+1, pair1  (gate: T+2 landed for next iter)
    PRD_B(1, 1);
    if (nl) PSTG_A(1, T + 3);
    BAR(); LGKM0;
    PRIO1; PMM(1); PRIO0;
    if (nl) { VMW(2); } else { VMW(0); }
    BAR();
  }
#undef PSTG_A
#undef PSTG_B
#undef PRD_A
#undef PRD_B
#undef PMM

  const int er = (lane >> 4) * 4, ec = lane & 15;
  const int r0 = mt * 128 + wm;
  const int c0 = nt * 256 + wn;
  float* C = out + (size_t)z * (2048 * 1024);
  const float* lz = lsum + z * 2048;
#pragma unroll
  for (int mi = 0; mi < 4; ++mi) {
    float inv[4];
#pragma unroll
    for (int r = 0; r < 4; ++r) inv[r] = 1.0f / lz[r0 + mi * 16 + er + r];
#pragma unroll
    for (int ni = 0; ni < 4; ++ni) {
      const int col = c0 + ni * 16 + ec;
#pragma unroll
      for (int r = 0; r < 4; ++r)
        C[(size_t)(r0 + mi * 16 + er + r) * 1024 + col] = acc[mi][ni][r] * inv[r];
    }
  }
}

extern "C" void kernel_launch(void* const* d_in, const int* in_sizes, int n_in,
                              void* d_out, int out_size, void* d_ws, size_t ws_size,
                              hipStream_t stream) {
  const float* x  = (const float*)d_in[0];
  const float* Wq = (const float*)d_in[1];
  const float* bq = (const float*)d_in[2];
  const float* Wk = (const float*)d_in[3];
  const float* bk = (const float*)d_in[4];
  const float* Wv = (const float*)d_in[5];
  const float* bv = (const float*)d_in[6];
  float* out = (float*)d_out;

  char* ws = (char*)d_ws;
  const size_t MB = 1ull << 20;
  u16* Q    = (u16*)(ws + 0 * MB);    // [2][8192][1024] bf16: Q,K contiguous
  u16* Vt   = (u16*)(ws + 48 * MB);   // [4][1024][2048]
  u16* Xb   = (u16*)(ws + 64 * MB);   // [8192][1024]
  u16* Wt   = (u16*)(ws + 80 * MB);   // [3][1024][1024]
  float* bias = (float*)(ws + 86 * MB);  // [3][1024]
  float* lsum = (float*)(ws + 87 * MB);  // [4][2048] softmax denominators
  u16* P    = (u16*)(ws + 88 * MB);   // [4][2048][2048] exp(scores), ends 120MB
  (void)ws_size; (void)in_sizes; (void)n_in; (void)out_size;

  // 1) fused prep: x->bf16, W->Wt, bias gather, lsum zero
  prep<<<11264, 256, 0, stream>>>(x, Wq, Wk, Wv, bq, bk, bv, Xb, Wt, bias, lsum);
  // 2) Q|K projection as one N=2048 GEMM (256 blocks, 8-phase)
  qk_proj<<<256, 512, 0, stream>>>(Xb, Wt, Q, bias);
  // 3) Vt projection + P~ = exp(Q K^T) with row sums (384 blocks, 8-phase)
  vt_score<<<384, 512, 0, stream>>>(Xb, Wt, Q, Vt, P, lsum, bias);
  // 4) out = (P~ V) / lsum[row] (256 blocks, 128x256, 4-phase)
  pv_out<<<256, 512, 0, stream>>>(P, Vt, out, lsum);
}